// Round 4
// baseline (308.891 us; speedup 1.0000x reference)
//
#include <hip/hip_runtime.h>
#include <math.h>

// Problem constants (from reference)
#define B_     1024
#define H_     200
#define W_     32
#define COUT_  16
#define TOPK_  50

#define XST 17   // x-tile stride (f32) for the 16 staged columns; odd -> 2-way bank aliasing = free
#define OST 17   // obuf stride (16 + 1 pad)

typedef _Float16 h2 __attribute__((ext_vector_type(2)));
typedef unsigned int u32x2 __attribute__((ext_vector_type(2)));
union HU { h2 h; int i; };

// Compile-time 64-bit lane mask for bitonic stage (J = exchange distance,
// K = block size). take_max(lane) = bit_J(lane) XOR bit_K(lane); K=64 -> bit_J.
constexpr unsigned long long lane_mask(int J, int K) {
    unsigned long long m = 0;
    for (int l = 0; l < 64; ++l) {
        bool a = (l & J) != 0;
        bool b = (K < 64) && ((l & K) != 0);
        if (a != b) m |= (1ull << l);
    }
    return m;
}

// Cross-lane XOR exchange on a 32-bit value (DPP / ds_swizzle paths).
template<int J>
__device__ __forceinline__ int lane_xor_i(int x) {
    if constexpr (J == 1)  return __builtin_amdgcn_update_dpp(x, x, 0xB1, 0xF, 0xF, true);  // quad_perm [1,0,3,2]
    else if constexpr (J == 2)  return __builtin_amdgcn_update_dpp(x, x, 0x4E, 0xF, 0xF, true);  // quad_perm [2,3,0,1]
    else if constexpr (J == 8)  return __builtin_amdgcn_update_dpp(x, x, 0x128, 0xF, 0xF, true); // row_ror:8 == xor8
    else /* J == 4 */           return __builtin_amdgcn_ds_swizzle(x, 0x101F); // BitMode xor=4
}

// Packed compare-exchange. J=16/32 use gfx950 v_permlane{16,32}_swap_b32:
// with both operands = v, the result pair per-lane is {self, partner(^J)},
// so pk_max/pk_min over the pair == max/min(self, partner). All-VALU, no
// LDS round-trip. Other J: exchange (DPP/ds_swizzle) + pk_max/pk_min.
// Selection: one v_cndmask_b32 with a compile-time SGPR-pair mask.
template<int J>
__device__ __forceinline__ void ce2m(int& v, unsigned long long mask) {
    int pa, pb;
    if constexpr (J == 16 || J == 32) {
#if __has_builtin(__builtin_amdgcn_permlane16_swap) && __has_builtin(__builtin_amdgcn_permlane32_swap)
        u32x2 r;
        if constexpr (J == 16) r = __builtin_amdgcn_permlane16_swap((unsigned)v, (unsigned)v, false, false);
        else                   r = __builtin_amdgcn_permlane32_swap((unsigned)v, (unsigned)v, false, false);
        pa = (int)r.x; pb = (int)r.y;
#else
        int a = v, b = v;
        if constexpr (J == 16) asm("v_permlane16_swap_b32 %0, %1" : "+v"(a), "+v"(b));
        else                   asm("v_permlane32_swap_b32 %0, %1" : "+v"(a), "+v"(b));
        pa = a; pb = b;
#endif
    } else {
        pa = v;
        pb = lane_xor_i<J>(v);
    }
    int mx, mn;
    asm("v_pk_max_f16 %0, %1, %2" : "=v"(mx) : "v"(pa), "v"(pb));
    asm("v_pk_min_f16 %0, %1, %2" : "=v"(mn) : "v"(pa), "v"(pb));
    asm("v_cndmask_b32 %0, %1, %2, %3" : "=v"(v) : "v"(mn), "v"(mx), "s"(mask));
}

// Plain packed max (for the merge steps).
__device__ __forceinline__ int pkmax(int a, int b) {
    int r;
    asm("v_pk_max_f16 %0, %1, %2" : "=v"(r) : "v"(a), "v"(b));
    return r;
}

// Bitonic stage on BOTH interleaved column-chains (a/b suffix = 2-way ILP;
// alternating gives the scheduler adjacent independent ops to fill latency).
#define CE4_3(J, K) { constexpr unsigned long long M = lane_mask(J, K); \
    ce2m<J>(v0a, M);  ce2m<J>(v0b, M); \
    ce2m<J>(v1a, ~M); ce2m<J>(v1b, ~M); \
    ce2m<J>(v2a, M);  ce2m<J>(v2b, M); }

// Chunk 3: only 8 real values (h=192..199), sort-8 descending.
#define CE3(J, K) { constexpr unsigned long long M = ~lane_mask(J, K); \
    ce2m<J>(v3a, M); ce2m<J>(v3b, M); }

// Applied only at writeout (monotonicity: top-k commutes with tanh).
__device__ __forceinline__ float fast_tanh(float s) {
    // tanh(s) = 1 - 2/(exp(2s)+1)
    float e = __expf(2.0f * s);
    return fmaf(-2.0f, __builtin_amdgcn_rcpf(e + 1.0f), 1.0f);
}

__global__ __launch_bounds__(256, 8) void cnn_topk_kernel(
    const float* __restrict__ x,     // [B,1,H,W]
    const float* __restrict__ cw,    // [COUT,1,3,1]
    const float* __restrict__ cb,    // [COUT]
    float* __restrict__ out)         // [B,COUT,TOPK,W]
{
    __shared__ float xs[(H_ + 2) * XST];   // 13736 B: only this block's 16 columns
    __shared__ int   obuf[TOPK_ * OST];    //  3400 B, per-cp packed results
    // total 17.1 KB -> 8 blocks/CU (thread-capped)

    const int b   = blockIdx.x >> 1;   // batch
    const int wh  = blockIdx.x & 1;    // 16-column half
    const int tid = threadIdx.x;
    const float* xb = x + (size_t)b * (H_ * W_) + wh * 16;

    // ---- stage the 16 needed columns of x[b] -> LDS, zero halo rows ----
    for (int i = tid; i < H_ * 4; i += 256) {       // 4 float4 per row
        int h = i >> 2, q = (i & 3) * 4;
        float4 v = *reinterpret_cast<const float4*>(xb + h * W_ + q);
        float* d = &xs[(h + 1) * XST + q];
        d[0] = v.x; d[1] = v.y; d[2] = v.z; d[3] = v.w;
    }
    if (tid < 16) {
        xs[tid] = 0.0f;
        xs[(H_ + 1) * XST + tid] = 0.0f;
    }
    __syncthreads();

    const int wave = tid >> 6;
    const int lane = tid & 63;

    const int SENT = (int)0xFC00FC00;  // packed f16 -inf sentinel (keys are raw conv scores)
    const int h3 = (192 + lane < H_) ? (192 + lane) : (H_ - 1);    // clamped tail row

    for (int cp = 0; cp < 8; ++cp) {
        const int coA = 2 * cp, coB = 2 * cp + 1;
        const float w0A = cw[coA * 3], w1A = cw[coA * 3 + 1], w2A = cw[coA * 3 + 2], bA = cb[coA];
        const float w0B = cw[coB * 3], w1B = cw[coB * 3 + 1], w2B = cw[coB * 3 + 2], bB = cb[coB];

#pragma unroll
        for (int wp = 0; wp < 2; ++wp) {
            const int wA = wave * 4 + wp * 2;      // local columns, two per pass
            const int wB = wA + 1;

            // conv only (NO tanh: monotone, applied post-selection).
            // Keys = raw conv scores packed to f16 via one v_cvt_pkrtz (monotone).
            int v0a, v1a, v2a, v3a, v0b, v1b, v2b, v3b;
#define MAKE_V(VR, HROW, WC)                                                 \
            {   const int hh = (HROW);                                       \
                float xm = xs[ hh      * XST + (WC)];                        \
                float xc = xs[(hh + 1) * XST + (WC)];                        \
                float xp = xs[(hh + 2) * XST + (WC)];                        \
                float sA = fmaf(w2A, xp, fmaf(w1A, xc, fmaf(w0A, xm, bA)));  \
                float sB = fmaf(w2B, xp, fmaf(w1B, xc, fmaf(w0B, xm, bB)));  \
                VR = __builtin_bit_cast(int, __builtin_amdgcn_cvt_pkrtz(sA, sB)); }
            MAKE_V(v0a, lane, wA)       MAKE_V(v0b, lane, wB)
            MAKE_V(v1a, 64 + lane, wA)  MAKE_V(v1b, 64 + lane, wB)
            MAKE_V(v2a, 128 + lane, wA) MAKE_V(v2b, 128 + lane, wB)
            MAKE_V(v3a, h3, wA)         MAKE_V(v3b, h3, wB)
#undef MAKE_V
            v3a = (lane < 8) ? v3a : SENT;   // tail chunk: 8 real values
            v3b = (lane < 8) ? v3b : SENT;

            // ---- sort chunks 0..2 (asc, desc, asc), 21 stages ----
            CE4_3(1, 2)
            CE4_3(2, 4)  CE4_3(1, 4)
            CE4_3(4, 8)  CE4_3(2, 8)  CE4_3(1, 8)
            CE4_3(8, 16) CE4_3(4, 16) CE4_3(2, 16) CE4_3(1, 16)
            CE4_3(16,32) CE4_3(8, 32) CE4_3(4, 32) CE4_3(2, 32) CE4_3(1, 32)
            CE4_3(32,64) CE4_3(16,64) CE4_3(8, 64) CE4_3(4, 64) CE4_3(2, 64) CE4_3(1, 64)

            // ---- chunk 3: sort-8 descending ----
            CE3(1, 2)
            CE3(2, 4)  CE3(1, 4)
            CE3(4, 8)  CE3(2, 8)  CE3(1, 8)

            // ---- top-64 merges ----
            int m1a = pkmax(v0a, v1a), m1b = pkmax(v0b, v1b);   // bitonic
            int m2a = pkmax(v2a, v3a), m2b = pkmax(v2b, v3b);   // bitonic
#define MM(J) { constexpr unsigned long long M = lane_mask(J, 64); \
                ce2m<J>(m1a, M);  ce2m<J>(m1b, M); \
                ce2m<J>(m2a, ~M); ce2m<J>(m2b, ~M); }
            MM(32) MM(16) MM(8) MM(4) MM(2) MM(1)
#undef MM
            int ta = pkmax(m1a, m2a), tb = pkmax(m1b, m2b);     // top-64 of 256, bitonic
#define MT(J) { constexpr unsigned long long M = ~lane_mask(J, 64); \
                ce2m<J>(ta, M); ce2m<J>(tb, M); }
            MT(32) MT(16) MT(8) MT(4) MT(2) MT(1)
#undef MT

            if (lane < TOPK_) {
                obuf[lane * OST + wA] = ta;
                obuf[lane * OST + wB] = tb;
            }
        }
        __syncthreads();   // all 16 w of this cp in obuf

        // ---- coalesced write-out for this co-pair (800 entries) ----
        // tanh applied HERE only: 50 per lane total vs 256 in the old loop.
#pragma unroll
        for (int j = 0; j < 4; ++j) {
            int idx = tid + j * 256;
            if (idx < 800) {
                int k = idx >> 4, w2 = idx & 15;
                HU u; u.i = obuf[k * OST + w2];
                size_t o0 = (((size_t)b * COUT_ + coA) * TOPK_ + k) * W_ + wh * 16 + w2;
                out[o0]                        = fast_tanh((float)u.h.x);
                out[o0 + (size_t)TOPK_ * W_]   = fast_tanh((float)u.h.y);
            }
        }
        __syncthreads();   // obuf free for next cp
    }
}

extern "C" void kernel_launch(void* const* d_in, const int* in_sizes, int n_in,
                              void* d_out, int out_size, void* d_ws, size_t ws_size,
                              hipStream_t stream) {
    const float* x  = (const float*)d_in[0];   // [1024,1,200,32]
    const float* cw = (const float*)d_in[1];   // [16,1,3,1]
    const float* cb = (const float*)d_in[2];   // [16]
    float* out = (float*)d_out;                // [1024,16,50,32]

    cnn_topk_kernel<<<dim3(B_ * 2), dim3(256), 0, stream>>>(x, cw, cb, out);
}

// Round 5
// 250.492 us; speedup vs baseline: 1.2331x; 1.2331x over previous
//
#include <hip/hip_runtime.h>
#include <math.h>

// Problem constants (from reference)
#define B_     1024
#define H_     200
#define W_     32
#define COUT_  16
#define TOPK_  50

#define XST 17   // x-tile stride (f32); odd -> 2-way bank aliasing = free
#define OST 17   // obuf stride (16 + 1 pad)

typedef _Float16 h2 __attribute__((ext_vector_type(2)));
union HU { h2 h; int i; };

// Compile-time 64-bit lane mask: take_max(lane) = bitJ(lane) XOR bitK(lane); K=64 -> bitJ.
constexpr unsigned long long lane_mask(int J, int K) {
    unsigned long long m = 0;
    for (int l = 0; l < 64; ++l) {
        bool a = (l & J) != 0;
        bool b = (K < 64) && ((l & K) != 0);
        if (a != b) m |= (1ull << l);
    }
    return m;
}

// ---- asm snippets -------------------------------------------------------
// Exchange per J: DPP (VALU) for 1,2,8; ds_swizzle for 4,16; ds_bpermute for 32.
#define X_1(o,v)  "v_mov_b32_dpp " o ", " v " quad_perm:[1,0,3,2] row_mask:0xf bank_mask:0xf\n\t"
#define X_2(o,v)  "v_mov_b32_dpp " o ", " v " quad_perm:[2,3,0,1] row_mask:0xf bank_mask:0xf\n\t"
#define X_8(o,v)  "v_mov_b32_dpp " o ", " v " row_ror:8 row_mask:0xf bank_mask:0xf\n\t"
#define X_4(o,v)  "ds_swizzle_b32 " o ", " v " offset:0x101F\n\t"
#define X_16(o,v) "ds_swizzle_b32 " o ", " v " offset:0x401F\n\t"
#define X_32(o,v) "ds_bpermute_b32 " o ", %[pa], " v "\n\t"
// DPP-after-EXEC-write needs 5 wait states (gfx9 hazard) -> s_nop 4 prologue.
#define PRE_1  "s_nop 4\n\t"
#define PRE_2  "s_nop 4\n\t"
#define PRE_8  "s_nop 4\n\t"
#define PRE_4  ""
#define PRE_16 ""
#define PRE_32 ""
// LDS-pipe exchanges need a wait before use.
#define WAIT_1  ""
#define WAIT_2  ""
#define WAIT_8  ""
#define WAIT_4  "s_waitcnt lgkmcnt(0)\n\t"
#define WAIT_16 "s_waitcnt lgkmcnt(0)\n\t"
#define WAIT_32 "s_waitcnt lgkmcnt(0)\n\t"

// Sort stage on 6 chains (v0a,v0b:take-max-in-M; v1a,v1b:in-~M; v2a,v2b:in-M).
// EXEC-masked pk_max/pk_min replaces per-chain cndmask: 3 SALU amortized over
// 6 chains, saving 6 VALU/stage. EXEC restored to -1 on exit.
#define S6(J, K) { constexpr unsigned long long M = lane_mask(J, K); \
  int o0,o1,o2,o3,o4,o5; \
  asm volatile( PRE_##J \
    X_##J("%[o0]","%[x0]") X_##J("%[o1]","%[x1]") X_##J("%[o2]","%[x2]") \
    X_##J("%[o3]","%[x3]") X_##J("%[o4]","%[x4]") X_##J("%[o5]","%[x5]") \
    WAIT_##J \
    "s_mov_b64 exec, %[m]\n\t" \
    "v_pk_max_f16 %[x0], %[x0], %[o0]\n\t" \
    "v_pk_max_f16 %[x1], %[x1], %[o1]\n\t" \
    "v_pk_min_f16 %[x2], %[x2], %[o2]\n\t" \
    "v_pk_min_f16 %[x3], %[x3], %[o3]\n\t" \
    "v_pk_max_f16 %[x4], %[x4], %[o4]\n\t" \
    "v_pk_max_f16 %[x5], %[x5], %[o5]\n\t" \
    "s_not_b64 exec, exec\n\t" \
    "v_pk_min_f16 %[x0], %[x0], %[o0]\n\t" \
    "v_pk_min_f16 %[x1], %[x1], %[o1]\n\t" \
    "v_pk_max_f16 %[x2], %[x2], %[o2]\n\t" \
    "v_pk_max_f16 %[x3], %[x3], %[o3]\n\t" \
    "v_pk_min_f16 %[x4], %[x4], %[o4]\n\t" \
    "v_pk_min_f16 %[x5], %[x5], %[o5]\n\t" \
    "s_mov_b64 exec, -1\n\t" \
    : [x0]"+v"(v0a),[x1]"+v"(v0b),[x2]"+v"(v1a),[x3]"+v"(v1b),[x4]"+v"(v2a),[x5]"+v"(v2b), \
      [o0]"=&v"(o0),[o1]"=&v"(o1),[o2]"=&v"(o2),[o3]"=&v"(o3),[o4]"=&v"(o4),[o5]"=&v"(o5) \
    : [m]"s"(M), [pa]"v"(paddr)); }

// Pair stage, take-MIN in lanes of lane_mask(J,K) (i.e. take-max in ~M):
// used for chunk-3 sort and final MT merges (both want max where bitJ^bitK clear).
#define P2N(J, K, A, B) { constexpr unsigned long long M = lane_mask(J, K); \
  int oA,oB; \
  asm volatile( PRE_##J \
    X_##J("%[xA2]","%[xA]") X_##J("%[xB2]","%[xB]") \
    WAIT_##J \
    "s_mov_b64 exec, %[m]\n\t" \
    "v_pk_min_f16 %[xA], %[xA], %[xA2]\n\t" \
    "v_pk_min_f16 %[xB], %[xB], %[xB2]\n\t" \
    "s_not_b64 exec, exec\n\t" \
    "v_pk_max_f16 %[xA], %[xA], %[xA2]\n\t" \
    "v_pk_max_f16 %[xB], %[xB], %[xB2]\n\t" \
    "s_mov_b64 exec, -1\n\t" \
    : [xA]"+v"(A),[xB]"+v"(B),[xA2]"=&v"(oA),[xB2]"=&v"(oB) \
    : [m]"s"(M), [pa]"v"(paddr)); }

// Merge stage on 4 chains: m1a,m1b take-max-in-M; m2a,m2b take-max-in-~M.
#define M4(J) { constexpr unsigned long long M = lane_mask(J, 64); \
  int o0,o1,o2,o3; \
  asm volatile( PRE_##J \
    X_##J("%[o0]","%[x0]") X_##J("%[o1]","%[x1]") X_##J("%[o2]","%[x2]") X_##J("%[o3]","%[x3]") \
    WAIT_##J \
    "s_mov_b64 exec, %[m]\n\t" \
    "v_pk_max_f16 %[x0], %[x0], %[o0]\n\t" \
    "v_pk_max_f16 %[x1], %[x1], %[o1]\n\t" \
    "v_pk_min_f16 %[x2], %[x2], %[o2]\n\t" \
    "v_pk_min_f16 %[x3], %[x3], %[o3]\n\t" \
    "s_not_b64 exec, exec\n\t" \
    "v_pk_min_f16 %[x0], %[x0], %[o0]\n\t" \
    "v_pk_min_f16 %[x1], %[x1], %[o1]\n\t" \
    "v_pk_max_f16 %[x2], %[x2], %[o2]\n\t" \
    "v_pk_max_f16 %[x3], %[x3], %[o3]\n\t" \
    "s_mov_b64 exec, -1\n\t" \
    : [x0]"+v"(m1a),[x1]"+v"(m1b),[x2]"+v"(m2a),[x3]"+v"(m2b), \
      [o0]"=&v"(o0),[o1]"=&v"(o1),[o2]"=&v"(o2),[o3]"=&v"(o3) \
    : [m]"s"(M), [pa]"v"(paddr)); }

// Plain packed max (full exec).
__device__ __forceinline__ int pkmax(int a, int b) {
    int r;
    asm("v_pk_max_f16 %0, %1, %2" : "=v"(r) : "v"(a), "v"(b));
    return r;
}

// Applied only at writeout (monotonicity: top-k commutes with tanh).
__device__ __forceinline__ float fast_tanh(float s) {
    float e = __expf(2.0f * s);
    return fmaf(-2.0f, __builtin_amdgcn_rcpf(e + 1.0f), 1.0f);
}

__global__ __launch_bounds__(256, 8) void cnn_topk_kernel(
    const float* __restrict__ x,     // [B,1,H,W]
    const float* __restrict__ cw,    // [COUT,1,3,1]
    const float* __restrict__ cb,    // [COUT]
    float* __restrict__ out)         // [B,COUT,TOPK,W]
{
    __shared__ float xs[(H_ + 2) * XST];   // 13736 B: only this block's 16 columns
    __shared__ int   obuf[TOPK_ * OST];    //  3400 B, per-cp packed results

    const int b   = blockIdx.x >> 1;   // batch
    const int wh  = blockIdx.x & 1;    // 16-column half
    const int tid = threadIdx.x;
    const float* xb = x + (size_t)b * (H_ * W_) + wh * 16;

    // ---- stage the 16 needed columns of x[b] -> LDS, zero halo rows ----
    for (int i = tid; i < H_ * 4; i += 256) {       // 4 float4 per row
        int h = i >> 2, q = (i & 3) * 4;
        float4 v = *reinterpret_cast<const float4*>(xb + h * W_ + q);
        float* d = &xs[(h + 1) * XST + q];
        d[0] = v.x; d[1] = v.y; d[2] = v.z; d[3] = v.w;
    }
    if (tid < 16) {
        xs[tid] = 0.0f;
        xs[(H_ + 1) * XST + tid] = 0.0f;
    }
    __syncthreads();

    const int wave = tid >> 6;
    const int lane = tid & 63;
    const int paddr = (lane ^ 32) << 2;   // bpermute address for J=32

    const int SENT = (int)0xFC00FC00;  // packed f16 -inf sentinel
    const int h3 = (192 + lane < H_) ? (192 + lane) : (H_ - 1);    // clamped tail row

#pragma unroll 1
    for (int cp = 0; cp < 8; ++cp) {
        const int coA = 2 * cp, coB = 2 * cp + 1;
        const float w0A = cw[coA * 3], w1A = cw[coA * 3 + 1], w2A = cw[coA * 3 + 2], bA = cb[coA];
        const float w0B = cw[coB * 3], w1B = cw[coB * 3 + 1], w2B = cw[coB * 3 + 2], bB = cb[coB];

#pragma unroll
        for (int wp = 0; wp < 2; ++wp) {
            const int wA = wave * 4 + wp * 2;      // local columns, two per pass
            const int wB = wA + 1;

            // conv only (tanh is monotone; applied post-selection at writeout).
            int v0a, v1a, v2a, v3a, v0b, v1b, v2b, v3b;
#define MAKE_V(VR, HROW, WC)                                                 \
            {   const int hh = (HROW);                                       \
                float xm = xs[ hh      * XST + (WC)];                        \
                float xc = xs[(hh + 1) * XST + (WC)];                        \
                float xp = xs[(hh + 2) * XST + (WC)];                        \
                float sA = fmaf(w2A, xp, fmaf(w1A, xc, fmaf(w0A, xm, bA)));  \
                float sB = fmaf(w2B, xp, fmaf(w1B, xc, fmaf(w0B, xm, bB)));  \
                VR = __builtin_bit_cast(int, __builtin_amdgcn_cvt_pkrtz(sA, sB)); }
            MAKE_V(v0a, lane, wA)       MAKE_V(v0b, lane, wB)
            MAKE_V(v1a, 64 + lane, wA)  MAKE_V(v1b, 64 + lane, wB)
            MAKE_V(v2a, 128 + lane, wA) MAKE_V(v2b, 128 + lane, wB)
            MAKE_V(v3a, h3, wA)         MAKE_V(v3b, h3, wB)
#undef MAKE_V
            v3a = (lane < 8) ? v3a : SENT;   // tail chunk: 8 real values
            v3b = (lane < 8) ? v3b : SENT;

            // ---- sort chunks 0..2 (asc, desc, asc), 21 stages ----
            S6(1, 2)
            S6(2, 4)  S6(1, 4)
            S6(4, 8)  S6(2, 8)  S6(1, 8)
            S6(8, 16) S6(4, 16) S6(2, 16) S6(1, 16)
            S6(16,32) S6(8, 32) S6(4, 32) S6(2, 32) S6(1, 32)
            S6(32,64) S6(16,64) S6(8, 64) S6(4, 64) S6(2, 64) S6(1, 64)

            // ---- chunk 3: sort-8 descending (take-max in ~lane_mask) ----
            P2N(1, 2, v3a, v3b)
            P2N(2, 4, v3a, v3b)  P2N(1, 4, v3a, v3b)
            P2N(4, 8, v3a, v3b)  P2N(2, 8, v3a, v3b)  P2N(1, 8, v3a, v3b)

            // ---- top-64 merges ----
            int m1a = pkmax(v0a, v1a), m1b = pkmax(v0b, v1b);   // bitonic
            int m2a = pkmax(v2a, v3a), m2b = pkmax(v2b, v3b);   // bitonic
            M4(32) M4(16) M4(8) M4(4) M4(2) M4(1)
            int ta = pkmax(m1a, m2a), tb = pkmax(m1b, m2b);     // top-64 of 256, bitonic
            P2N(32, 64, ta, tb) P2N(16, 64, ta, tb) P2N(8, 64, ta, tb)
            P2N(4, 64, ta, tb)  P2N(2, 64, ta, tb)  P2N(1, 64, ta, tb)

            if (lane < TOPK_) {
                obuf[lane * OST + wA] = ta;
                obuf[lane * OST + wB] = tb;
            }
        }
        __syncthreads();   // all 16 w of this cp in obuf

        // ---- coalesced write-out for this co-pair (800 entries) ----
#pragma unroll
        for (int j = 0; j < 4; ++j) {
            int idx = tid + j * 256;
            if (idx < 800) {
                int k = idx >> 4, w2 = idx & 15;
                HU u; u.i = obuf[k * OST + w2];
                size_t o0 = (((size_t)b * COUT_ + coA) * TOPK_ + k) * W_ + wh * 16 + w2;
                out[o0]                        = fast_tanh((float)u.h.x);
                out[o0 + (size_t)TOPK_ * W_]   = fast_tanh((float)u.h.y);
            }
        }
        __syncthreads();   // obuf free for next cp
    }
}

extern "C" void kernel_launch(void* const* d_in, const int* in_sizes, int n_in,
                              void* d_out, int out_size, void* d_ws, size_t ws_size,
                              hipStream_t stream) {
    const float* x  = (const float*)d_in[0];   // [1024,1,200,32]
    const float* cw = (const float*)d_in[1];   // [16,1,3,1]
    const float* cb = (const float*)d_in[2];   // [16]
    float* out = (float*)d_out;                // [1024,16,50,32]

    cnn_topk_kernel<<<dim3(B_ * 2), dim3(256), 0, stream>>>(x, cw, cb, out);
}

// Round 6
// 230.002 us; speedup vs baseline: 1.3430x; 1.0891x over previous
//
#include <hip/hip_runtime.h>
#include <math.h>

// Problem constants (from reference)
#define B_     1024
#define H_     200
#define W_     32
#define COUT_  16
#define TOPK_  50

#define XST 17   // x-tile stride (f32)
#define OST 17   // obuf stride (16 + 1 pad)

typedef _Float16 h2 __attribute__((ext_vector_type(2)));
union HU { h2 h; int i; };

// Layout: column = lane>>4, ln = lane&15. Per column 256 h-slots:
// h = chunk*64 + r*16 + ln, chunks in regs a0..a3 (c0), b0..b3 (c1),
// e0..e3 (c2), f0 (c3: 8 real values). Chunk dirs: asc, desc, asc, desc.
// take_max(x) = bit_d(x) ^ bit_K(x) ^ D ; bit4 = r&1, bit5 = r>>1.

// Lane-mask over ln bits (replicated to all four 16-lane groups).
constexpr unsigned long long lmask(int d, int Kb) {
    unsigned long long m = 0;
    for (int l = 0; l < 64; ++l) {
        int ln = l & 15;
        bool a = (ln & d) != 0;
        bool b = Kb && ((ln & Kb) != 0);
        if (a != b) m |= (1ull << l);
    }
    return m;
}

// ---- asm snippets -------------------------------------------------------
#define XOP_1(o,v) "v_mov_b32_dpp " o ", " v " quad_perm:[1,0,3,2] row_mask:0xf bank_mask:0xf\n\t"
#define XOP_2(o,v) "v_mov_b32_dpp " o ", " v " quad_perm:[2,3,0,1] row_mask:0xf bank_mask:0xf\n\t"
#define XOP_8(o,v) "v_mov_b32_dpp " o ", " v " row_ror:8 row_mask:0xf bank_mask:0xf\n\t"
#define XOP_4(o,v) "ds_swizzle_b32 " o ", " v " offset:0x101F\n\t"
#define PRE_1 "s_nop 4\n\t"
#define PRE_2 "s_nop 4\n\t"
#define PRE_8 "s_nop 4\n\t"
#define PRE_4 ""
#define WAIT_1 ""
#define WAIT_2 ""
#define WAIT_8 ""
#define WAIT_4 "s_waitcnt lgkmcnt(0)\n\t"

// Phase-op token expansion: phase1 uses the listed op, phase2 the opposite.
#define P1_MX "v_pk_max_f16 "
#define P1_MN "v_pk_min_f16 "
#define P2_MX "v_pk_min_f16 "
#define P2_MN "v_pk_max_f16 "
#define OP_(ph,t,x,o) ph##_##t x ", " x ", " o "\n\t"

// 12-reg EXEC-masked lane stage on a0..a3,b0..b3,e0..e3.
#define SRT12(d, Kb, t0,t1,t2,t3,t4,t5,t6,t7,t8,t9,tA,tB) { \
  constexpr unsigned long long M_ = lmask(d, Kb); \
  int o0,o1,o2,o3,o4,o5,o6,o7,o8,o9,oA,oB; \
  asm volatile( PRE_##d \
    XOP_##d("%[o0]","%[x0]") XOP_##d("%[o1]","%[x1]") \
    XOP_##d("%[o2]","%[x2]") XOP_##d("%[o3]","%[x3]") \
    XOP_##d("%[o4]","%[x4]") XOP_##d("%[o5]","%[x5]") \
    XOP_##d("%[o6]","%[x6]") XOP_##d("%[o7]","%[x7]") \
    XOP_##d("%[o8]","%[x8]") XOP_##d("%[o9]","%[x9]") \
    XOP_##d("%[oA]","%[xA]") XOP_##d("%[oB]","%[xB]") \
    WAIT_##d \
    "s_mov_b64 exec, %[m]\n\t" \
    OP_(P1,t0,"%[x0]","%[o0]") OP_(P1,t1,"%[x1]","%[o1]") \
    OP_(P1,t2,"%[x2]","%[o2]") OP_(P1,t3,"%[x3]","%[o3]") \
    OP_(P1,t4,"%[x4]","%[o4]") OP_(P1,t5,"%[x5]","%[o5]") \
    OP_(P1,t6,"%[x6]","%[o6]") OP_(P1,t7,"%[x7]","%[o7]") \
    OP_(P1,t8,"%[x8]","%[o8]") OP_(P1,t9,"%[x9]","%[o9]") \
    OP_(P1,tA,"%[xA]","%[oA]") OP_(P1,tB,"%[xB]","%[oB]") \
    "s_not_b64 exec, exec\n\t" \
    OP_(P2,t0,"%[x0]","%[o0]") OP_(P2,t1,"%[x1]","%[o1]") \
    OP_(P2,t2,"%[x2]","%[o2]") OP_(P2,t3,"%[x3]","%[o3]") \
    OP_(P2,t4,"%[x4]","%[o4]") OP_(P2,t5,"%[x5]","%[o5]") \
    OP_(P2,t6,"%[x6]","%[o6]") OP_(P2,t7,"%[x7]","%[o7]") \
    OP_(P2,t8,"%[x8]","%[o8]") OP_(P2,t9,"%[x9]","%[o9]") \
    OP_(P2,tA,"%[xA]","%[oA]") OP_(P2,tB,"%[xB]","%[oB]") \
    "s_mov_b64 exec, -1\n\t" \
    : [x0]"+v"(a0),[x1]"+v"(a1),[x2]"+v"(a2),[x3]"+v"(a3), \
      [x4]"+v"(b0),[x5]"+v"(b1),[x6]"+v"(b2),[x7]"+v"(b3), \
      [x8]"+v"(e0),[x9]"+v"(e1),[xA]"+v"(e2),[xB]"+v"(e3), \
      [o0]"=&v"(o0),[o1]"=&v"(o1),[o2]"=&v"(o2),[o3]"=&v"(o3), \
      [o4]"=&v"(o4),[o5]"=&v"(o5),[o6]"=&v"(o6),[o7]"=&v"(o7), \
      [o8]"=&v"(o8),[o9]"=&v"(o9),[oA]"=&v"(oA),[oB]"=&v"(oB) \
    : [m]"s"(M_)); }

// K<=8 blocks and K=64 sub-stages: flip = chunk dir (asc,desc,asc)
#define SRT_A(d,Kb) SRT12(d,Kb, MX,MX,MX,MX, MN,MN,MN,MN, MX,MX,MX,MX)
// K=16 sub-stages: flip = (r&1) ^ D
#define SRT_B(d)    SRT12(d,0,  MX,MN,MX,MN, MN,MX,MN,MX, MX,MN,MX,MN)
// K=32 sub-stages: flip = (r>>1) ^ D
#define SRT_C(d)    SRT12(d,0,  MX,MX,MN,MN, MN,MN,MX,MX, MX,MX,MN,MN)

// chunk3 (f0) stage, desc (phase1 = min).
#define C3(d, Kb) { constexpr unsigned long long M_ = lmask(d, Kb); int oF; \
  asm volatile( PRE_##d XOP_##d("%[oF]","%[xF]") WAIT_##d \
    "s_mov_b64 exec, %[m]\n\t" \
    "v_pk_min_f16 %[xF], %[xF], %[oF]\n\t" \
    "s_not_b64 exec, exec\n\t" \
    "v_pk_max_f16 %[xF], %[xF], %[oF]\n\t" \
    "s_mov_b64 exec, -1\n\t" \
    : [xF]"+v"(f0), [oF]"=&v"(oF) : [m]"s"(M_)); }

// merge cleanup lane stage: g0..g3 asc (phase1 max), e0..e3 desc (phase1 min)
#define MRG8(d) { constexpr unsigned long long M_ = lmask(d, 0); \
  int o0,o1,o2,o3,o4,o5,o6,o7; \
  asm volatile( PRE_##d \
    XOP_##d("%[o0]","%[x0]") XOP_##d("%[o1]","%[x1]") \
    XOP_##d("%[o2]","%[x2]") XOP_##d("%[o3]","%[x3]") \
    XOP_##d("%[o4]","%[x4]") XOP_##d("%[o5]","%[x5]") \
    XOP_##d("%[o6]","%[x6]") XOP_##d("%[o7]","%[x7]") \
    WAIT_##d \
    "s_mov_b64 exec, %[m]\n\t" \
    "v_pk_max_f16 %[x0], %[x0], %[o0]\n\t" \
    "v_pk_max_f16 %[x1], %[x1], %[o1]\n\t" \
    "v_pk_max_f16 %[x2], %[x2], %[o2]\n\t" \
    "v_pk_max_f16 %[x3], %[x3], %[o3]\n\t" \
    "v_pk_min_f16 %[x4], %[x4], %[o4]\n\t" \
    "v_pk_min_f16 %[x5], %[x5], %[o5]\n\t" \
    "v_pk_min_f16 %[x6], %[x6], %[o6]\n\t" \
    "v_pk_min_f16 %[x7], %[x7], %[o7]\n\t" \
    "s_not_b64 exec, exec\n\t" \
    "v_pk_min_f16 %[x0], %[x0], %[o0]\n\t" \
    "v_pk_min_f16 %[x1], %[x1], %[o1]\n\t" \
    "v_pk_min_f16 %[x2], %[x2], %[o2]\n\t" \
    "v_pk_min_f16 %[x3], %[x3], %[o3]\n\t" \
    "v_pk_max_f16 %[x4], %[x4], %[o4]\n\t" \
    "v_pk_max_f16 %[x5], %[x5], %[o5]\n\t" \
    "v_pk_max_f16 %[x6], %[x6], %[o6]\n\t" \
    "v_pk_max_f16 %[x7], %[x7], %[o7]\n\t" \
    "s_mov_b64 exec, -1\n\t" \
    : [x0]"+v"(g0),[x1]"+v"(g1),[x2]"+v"(g2),[x3]"+v"(g3), \
      [x4]"+v"(e0),[x5]"+v"(e1),[x6]"+v"(e2),[x7]"+v"(e3), \
      [o0]"=&v"(o0),[o1]"=&v"(o1),[o2]"=&v"(o2),[o3]"=&v"(o3), \
      [o4]"=&v"(o4),[o5]"=&v"(o5),[o6]"=&v"(o6),[o7]"=&v"(o7) \
    : [m]"s"(M_)); }

// final desc stage on g0..g3 (phase1 min)
#define FIN4(d) { constexpr unsigned long long M_ = lmask(d, 0); \
  int o0,o1,o2,o3; \
  asm volatile( PRE_##d \
    XOP_##d("%[o0]","%[x0]") XOP_##d("%[o1]","%[x1]") \
    XOP_##d("%[o2]","%[x2]") XOP_##d("%[o3]","%[x3]") \
    WAIT_##d \
    "s_mov_b64 exec, %[m]\n\t" \
    "v_pk_min_f16 %[x0], %[x0], %[o0]\n\t" \
    "v_pk_min_f16 %[x1], %[x1], %[o1]\n\t" \
    "v_pk_min_f16 %[x2], %[x2], %[o2]\n\t" \
    "v_pk_min_f16 %[x3], %[x3], %[o3]\n\t" \
    "s_not_b64 exec, exec\n\t" \
    "v_pk_max_f16 %[x0], %[x0], %[o0]\n\t" \
    "v_pk_max_f16 %[x1], %[x1], %[o1]\n\t" \
    "v_pk_max_f16 %[x2], %[x2], %[o2]\n\t" \
    "v_pk_max_f16 %[x3], %[x3], %[o3]\n\t" \
    "s_mov_b64 exec, -1\n\t" \
    : [x0]"+v"(g0),[x1]"+v"(g1),[x2]"+v"(g2),[x3]"+v"(g3), \
      [o0]"=&v"(o0),[o1]"=&v"(o1),[o2]"=&v"(o2),[o3]"=&v"(o3) \
    : [m]"s"(M_)); }

__device__ __forceinline__ int pkmx(int a, int b) {
    int r; asm("v_pk_max_f16 %0, %1, %2" : "=v"(r) : "v"(a), "v"(b)); return r;
}
__device__ __forceinline__ int pkmn(int a, int b) {
    int r; asm("v_pk_min_f16 %0, %1, %2" : "=v"(r) : "v"(a), "v"(b)); return r;
}
// Register-level CE (d=16/32): compile-time direction -> pure rename.
#define RCE(A,B,FLIP) { int mn_ = pkmn(A,B), mx_ = pkmx(A,B); \
  if (FLIP) { A = mx_; B = mn_; } else { A = mn_; B = mx_; } }

// Applied only at writeout (monotonicity: top-k commutes with tanh).
__device__ __forceinline__ float fast_tanh(float s) {
    float e = __expf(2.0f * s);
    return fmaf(-2.0f, __builtin_amdgcn_rcpf(e + 1.0f), 1.0f);
}

__global__ __launch_bounds__(256, 8) void cnn_topk_kernel(
    const float* __restrict__ x,     // [B,1,H,W]
    const float* __restrict__ cw,    // [COUT,1,3,1]
    const float* __restrict__ cb,    // [COUT]
    float* __restrict__ out)         // [B,COUT,TOPK,W]
{
    __shared__ float xs[(H_ + 2) * XST];   // 13736 B
    __shared__ int   obuf[TOPK_ * OST];    //  3400 B

    const int b   = blockIdx.x >> 1;
    const int wh  = blockIdx.x & 1;
    const int tid = threadIdx.x;
    const float* xb = x + (size_t)b * (H_ * W_) + wh * 16;

    // ---- stage the 16 needed columns of x[b] -> LDS, zero halo rows ----
    for (int i = tid; i < H_ * 4; i += 256) {
        int h = i >> 2, q = (i & 3) * 4;
        float4 v = *reinterpret_cast<const float4*>(xb + h * W_ + q);
        float* d = &xs[(h + 1) * XST + q];
        d[0] = v.x; d[1] = v.y; d[2] = v.z; d[3] = v.w;
    }
    if (tid < 16) {
        xs[tid] = 0.0f;
        xs[(H_ + 1) * XST + tid] = 0.0f;
    }
    __syncthreads();

    const int wave = tid >> 6;
    const int lane = tid & 63;
    const int ln   = lane & 15;
    const int col  = wave * 4 + (lane >> 4);   // local column 0..15

    const int SENT = (int)0xFC00FC00;          // packed f16 -inf
    const bool tail_ok = (ln < 8);
    const int h3t = (192 + ln < H_) ? (192 + ln) : (H_ - 1);
    const float* xsf = &xs[ln * XST + col];    // base for rows C+ln
    const float* xst = &xs[h3t * XST + col];   // tail base
    int* obase = &obuf[ln * OST + col];

#pragma unroll 1
    for (int cp = 0; cp < 8; ++cp) {
        const int coA = 2 * cp, coB = 2 * cp + 1;
        const float w0A = cw[coA * 3], w1A = cw[coA * 3 + 1], w2A = cw[coA * 3 + 2], bA = cb[coA];
        const float w0B = cw[coB * 3], w1B = cw[coB * 3 + 1], w2B = cw[coB * 3 + 2], bB = cb[coB];

        // conv only (tanh applied post-selection). h = CO + ln.
        int a0,a1,a2,a3,b0,b1,b2,b3,e0,e1,e2,e3,f0;
#define CONV1(VR, CO) { \
        float xm = xsf[(CO)*XST], xc = xsf[((CO)+1)*XST], xp = xsf[((CO)+2)*XST]; \
        float sA = fmaf(w2A, xp, fmaf(w1A, xc, fmaf(w0A, xm, bA))); \
        float sB = fmaf(w2B, xp, fmaf(w1B, xc, fmaf(w0B, xm, bB))); \
        VR = __builtin_bit_cast(int, __builtin_amdgcn_cvt_pkrtz(sA, sB)); }
        CONV1(a0, 0)   CONV1(a1, 16)  CONV1(a2, 32)  CONV1(a3, 48)
        CONV1(b0, 64)  CONV1(b1, 80)  CONV1(b2, 96)  CONV1(b3, 112)
        CONV1(e0, 128) CONV1(e1, 144) CONV1(e2, 160) CONV1(e3, 176)
        { float xm = xst[0], xc = xst[XST], xp = xst[2*XST];
          float sA = fmaf(w2A, xp, fmaf(w1A, xc, fmaf(w0A, xm, bA)));
          float sB = fmaf(w2B, xp, fmaf(w1B, xc, fmaf(w0B, xm, bB)));
          int vt = __builtin_bit_cast(int, __builtin_amdgcn_cvt_pkrtz(sA, sB));
          f0 = tail_ok ? vt : SENT; }
#undef CONV1

        // ---- sort chunks 0..2 (asc,desc,asc), 64-sort each ----
        SRT_A(1, 2)                            // K=2
        SRT_A(2, 4) SRT_A(1, 4)                // K=4
        SRT_A(4, 8) SRT_A(2, 8) SRT_A(1, 8)    // K=8
        SRT_B(8) SRT_B(4) SRT_B(2) SRT_B(1)    // K=16
        RCE(a0,a1,0) RCE(a2,a3,1) RCE(b0,b1,1) RCE(b2,b3,0) RCE(e0,e1,0) RCE(e2,e3,1) // K=32 d16
        SRT_C(8) SRT_C(4) SRT_C(2) SRT_C(1)    // K=32
        RCE(a0,a2,0) RCE(a1,a3,0) RCE(b0,b2,1) RCE(b1,b3,1) RCE(e0,e2,0) RCE(e1,e3,0) // K=64 d32
        RCE(a0,a1,0) RCE(a2,a3,0) RCE(b0,b1,1) RCE(b2,b3,1) RCE(e0,e1,0) RCE(e2,e3,0) // K=64 d16
        SRT_A(8, 0) SRT_A(4, 0) SRT_A(2, 0) SRT_A(1, 0)   // K=64

        // ---- chunk3 sort-8 desc ----
        C3(1, 2) C3(2, 4) C3(1, 4) C3(4, 0) C3(2, 0) C3(1, 0)

        // ---- merges: top-64 of 256 ----
        int g0 = pkmx(a0, b0), g1 = pkmx(a1, b1), g2 = pkmx(a2, b2), g3 = pkmx(a3, b3);
        e0 = pkmx(e0, f0);                    // m2 = max(c2, c3); e1..e3 unchanged
        RCE(g0,g2,0) RCE(g1,g3,0) RCE(e0,e2,1) RCE(e1,e3,1)   // d32
        RCE(g0,g1,0) RCE(g2,g3,0) RCE(e0,e1,1) RCE(e2,e3,1)   // d16
        MRG8(8) MRG8(4) MRG8(2) MRG8(1)        // m1 asc, m2 desc
        g0 = pkmx(g0, e0); g1 = pkmx(g1, e1); g2 = pkmx(g2, e2); g3 = pkmx(g3, e3);
        RCE(g0,g2,1) RCE(g1,g3,1)              // d32 desc
        RCE(g0,g1,1) RCE(g2,g3,1)              // d16 desc
        FIN4(8) FIN4(4) FIN4(2) FIN4(1)        // sorted desc; rank = r*16+ln

        obase[0]            = g0;              // ranks  0..15
        obase[16 * OST]     = g1;              // ranks 16..31
        obase[32 * OST]     = g2;              // ranks 32..47
        if (ln < 2) obase[48 * OST] = g3;      // ranks 48,49
        __syncthreads();   // all 16 w of this cp in obuf

        // ---- coalesced write-out for this co-pair (800 entries) ----
#pragma unroll
        for (int j = 0; j < 4; ++j) {
            int idx = tid + j * 256;
            if (idx < 800) {
                int k = idx >> 4, w2 = idx & 15;
                HU u; u.i = obuf[k * OST + w2];
                size_t o0 = (((size_t)b * COUT_ + coA) * TOPK_ + k) * W_ + wh * 16 + w2;
                out[o0]                        = fast_tanh((float)u.h.x);
                out[o0 + (size_t)TOPK_ * W_]   = fast_tanh((float)u.h.y);
            }
        }
        __syncthreads();   // obuf free for next cp
    }
}

extern "C" void kernel_launch(void* const* d_in, const int* in_sizes, int n_in,
                              void* d_out, int out_size, void* d_ws, size_t ws_size,
                              hipStream_t stream) {
    const float* x  = (const float*)d_in[0];   // [1024,1,200,32]
    const float* cw = (const float*)d_in[1];   // [16,1,3,1]
    const float* cb = (const float*)d_in[2];   // [16]
    float* out = (float*)d_out;                // [1024,16,50,32]

    cnn_topk_kernel<<<dim3(B_ * 2), dim3(256), 0, stream>>>(x, cw, cb, out);
}

// Round 8
// 218.531 us; speedup vs baseline: 1.4135x; 1.0525x over previous
//
#include <hip/hip_runtime.h>
#include <math.h>

// Problem constants (from reference)
#define B_     1024
#define H_     200
#define W_     32
#define COUT_  16
#define TOPK_  50

#define CST 208  // x-tile column stride (f32): 208 mod 32 = 16 -> conv reads exactly 2-way
#define OST 17   // obuf stride (16 + 1 pad)

typedef _Float16 h2 __attribute__((ext_vector_type(2)));
union HU { h2 h; int i; };

// Layout: column = lane>>4, ln = lane&15. Per column 256 h-slots:
// h = chunk*64 + r*16 + ln, chunks in regs a0..a3 (c0), b0..b3 (c1),
// e0..e3 (c2), f0 (c3: 8 real values). Chunk dirs: asc, desc, asc, desc.

// Lane-mask over ln bits (replicated to all four 16-lane groups).
constexpr unsigned long long lmask(int d, int Kb) {
    unsigned long long m = 0;
    for (int l = 0; l < 64; ++l) {
        int ln = l & 15;
        bool a = (ln & d) != 0;
        bool b = Kb && ((ln & Kb) != 0);
        if (a != b) m |= (1ull << l);
    }
    return m;
}

// ---- asm snippets -------------------------------------------------------
// Pipe split: d=1 on DPP (VALU), d=2,4,8 on ds_swizzle (LDS pipe) to balance
// VALU (~69% busy) vs LDS (~33% busy) — R4/R5 showed LDS pipe is cheaper.
#define XOP_1(o,v) "v_mov_b32_dpp " o ", " v " quad_perm:[1,0,3,2] row_mask:0xf bank_mask:0xf\n\t"
#define XOP_2(o,v) "ds_swizzle_b32 " o ", " v " offset:0x081F\n\t"
#define XOP_4(o,v) "ds_swizzle_b32 " o ", " v " offset:0x101F\n\t"
#define XOP_8(o,v) "ds_swizzle_b32 " o ", " v " offset:0x201F\n\t"
#define PRE_1 "s_nop 4\n\t"
#define PRE_2 ""
#define PRE_4 ""
#define PRE_8 ""
#define WAIT_1 ""
#define WAIT_2 "s_waitcnt lgkmcnt(0)\n\t"
#define WAIT_4 "s_waitcnt lgkmcnt(0)\n\t"
#define WAIT_8 "s_waitcnt lgkmcnt(0)\n\t"

// Phase-op token expansion: phase1 uses the listed op, phase2 the opposite.
#define P1_MX "v_pk_max_f16 "
#define P1_MN "v_pk_min_f16 "
#define P2_MX "v_pk_min_f16 "
#define P2_MN "v_pk_max_f16 "
#define OP_(ph,t,x,o) ph##_##t x ", " x ", " o "\n\t"

// 12-reg EXEC-masked lane stage on a0..a3,b0..b3,e0..e3.
#define SRT12(d, Kb, t0,t1,t2,t3,t4,t5,t6,t7,t8,t9,tA,tB) { \
  constexpr unsigned long long M_ = lmask(d, Kb); \
  int o0,o1,o2,o3,o4,o5,o6,o7,o8,o9,oA,oB; \
  asm volatile( PRE_##d \
    XOP_##d("%[o0]","%[x0]") XOP_##d("%[o1]","%[x1]") \
    XOP_##d("%[o2]","%[x2]") XOP_##d("%[o3]","%[x3]") \
    XOP_##d("%[o4]","%[x4]") XOP_##d("%[o5]","%[x5]") \
    XOP_##d("%[o6]","%[x6]") XOP_##d("%[o7]","%[x7]") \
    XOP_##d("%[o8]","%[x8]") XOP_##d("%[o9]","%[x9]") \
    XOP_##d("%[oA]","%[xA]") XOP_##d("%[oB]","%[xB]") \
    WAIT_##d \
    "s_mov_b64 exec, %[m]\n\t" \
    OP_(P1,t0,"%[x0]","%[o0]") OP_(P1,t1,"%[x1]","%[o1]") \
    OP_(P1,t2,"%[x2]","%[o2]") OP_(P1,t3,"%[x3]","%[o3]") \
    OP_(P1,t4,"%[x4]","%[o4]") OP_(P1,t5,"%[x5]","%[o5]") \
    OP_(P1,t6,"%[x6]","%[o6]") OP_(P1,t7,"%[x7]","%[o7]") \
    OP_(P1,t8,"%[x8]","%[o8]") OP_(P1,t9,"%[x9]","%[o9]") \
    OP_(P1,tA,"%[xA]","%[oA]") OP_(P1,tB,"%[xB]","%[oB]") \
    "s_not_b64 exec, exec\n\t" \
    OP_(P2,t0,"%[x0]","%[o0]") OP_(P2,t1,"%[x1]","%[o1]") \
    OP_(P2,t2,"%[x2]","%[o2]") OP_(P2,t3,"%[x3]","%[o3]") \
    OP_(P2,t4,"%[x4]","%[o4]") OP_(P2,t5,"%[x5]","%[o5]") \
    OP_(P2,t6,"%[x6]","%[o6]") OP_(P2,t7,"%[x7]","%[o7]") \
    OP_(P2,t8,"%[x8]","%[o8]") OP_(P2,t9,"%[x9]","%[o9]") \
    OP_(P2,tA,"%[xA]","%[oA]") OP_(P2,tB,"%[xB]","%[oB]") \
    "s_mov_b64 exec, -1\n\t" \
    : [x0]"+v"(a0),[x1]"+v"(a1),[x2]"+v"(a2),[x3]"+v"(a3), \
      [x4]"+v"(b0),[x5]"+v"(b1),[x6]"+v"(b2),[x7]"+v"(b3), \
      [x8]"+v"(e0),[x9]"+v"(e1),[xA]"+v"(e2),[xB]"+v"(e3), \
      [o0]"=&v"(o0),[o1]"=&v"(o1),[o2]"=&v"(o2),[o3]"=&v"(o3), \
      [o4]"=&v"(o4),[o5]"=&v"(o5),[o6]"=&v"(o6),[o7]"=&v"(o7), \
      [o8]"=&v"(o8),[o9]"=&v"(o9),[oA]"=&v"(oA),[oB]"=&v"(oB) \
    : [m]"s"(M_)); }

// K<=8 blocks and K=64 sub-stages: flip = chunk dir (asc,desc,asc)
#define SRT_A(d,Kb) SRT12(d,Kb, MX,MX,MX,MX, MN,MN,MN,MN, MX,MX,MX,MX)
// K=16 sub-stages: flip = (r&1) ^ D
#define SRT_B(d)    SRT12(d,0,  MX,MN,MX,MN, MN,MX,MN,MX, MX,MN,MX,MN)
// K=32 sub-stages: flip = (r>>1) ^ D
#define SRT_C(d)    SRT12(d,0,  MX,MX,MN,MN, MN,MN,MX,MX, MX,MX,MN,MN)

// chunk3 (f0) stage, desc (phase1 = min).
#define C3(d, Kb) { constexpr unsigned long long M_ = lmask(d, Kb); int oF; \
  asm volatile( PRE_##d XOP_##d("%[oF]","%[xF]") WAIT_##d \
    "s_mov_b64 exec, %[m]\n\t" \
    "v_pk_min_f16 %[xF], %[xF], %[oF]\n\t" \
    "s_not_b64 exec, exec\n\t" \
    "v_pk_max_f16 %[xF], %[xF], %[oF]\n\t" \
    "s_mov_b64 exec, -1\n\t" \
    : [xF]"+v"(f0), [oF]"=&v"(oF) : [m]"s"(M_)); }

// merge cleanup lane stage: g0..g3 asc (phase1 max), e0..e3 desc (phase1 min)
#define MRG8(d) { constexpr unsigned long long M_ = lmask(d, 0); \
  int o0,o1,o2,o3,o4,o5,o6,o7; \
  asm volatile( PRE_##d \
    XOP_##d("%[o0]","%[x0]") XOP_##d("%[o1]","%[x1]") \
    XOP_##d("%[o2]","%[x2]") XOP_##d("%[o3]","%[x3]") \
    XOP_##d("%[o4]","%[x4]") XOP_##d("%[o5]","%[x5]") \
    XOP_##d("%[o6]","%[x6]") XOP_##d("%[o7]","%[x7]") \
    WAIT_##d \
    "s_mov_b64 exec, %[m]\n\t" \
    "v_pk_max_f16 %[x0], %[x0], %[o0]\n\t" \
    "v_pk_max_f16 %[x1], %[x1], %[o1]\n\t" \
    "v_pk_max_f16 %[x2], %[x2], %[o2]\n\t" \
    "v_pk_max_f16 %[x3], %[x3], %[o3]\n\t" \
    "v_pk_min_f16 %[x4], %[x4], %[o4]\n\t" \
    "v_pk_min_f16 %[x5], %[x5], %[o5]\n\t" \
    "v_pk_min_f16 %[x6], %[x6], %[o6]\n\t" \
    "v_pk_min_f16 %[x7], %[x7], %[o7]\n\t" \
    "s_not_b64 exec, exec\n\t" \
    "v_pk_min_f16 %[x0], %[x0], %[o0]\n\t" \
    "v_pk_min_f16 %[x1], %[x1], %[o1]\n\t" \
    "v_pk_min_f16 %[x2], %[x2], %[o2]\n\t" \
    "v_pk_min_f16 %[x3], %[x3], %[o3]\n\t" \
    "v_pk_max_f16 %[x4], %[x4], %[o4]\n\t" \
    "v_pk_max_f16 %[x5], %[x5], %[o5]\n\t" \
    "v_pk_max_f16 %[x6], %[x6], %[o6]\n\t" \
    "v_pk_max_f16 %[x7], %[x7], %[o7]\n\t" \
    "s_mov_b64 exec, -1\n\t" \
    : [x0]"+v"(g0),[x1]"+v"(g1),[x2]"+v"(g2),[x3]"+v"(g3), \
      [x4]"+v"(e0),[x5]"+v"(e1),[x6]"+v"(e2),[x7]"+v"(e3), \
      [o0]"=&v"(o0),[o1]"=&v"(o1),[o2]"=&v"(o2),[o3]"=&v"(o3), \
      [o4]"=&v"(o4),[o5]"=&v"(o5),[o6]"=&v"(o6),[o7]"=&v"(o7) \
    : [m]"s"(M_)); }

// final desc stage on g0..g3 (phase1 min)
#define FIN4(d) { constexpr unsigned long long M_ = lmask(d, 0); \
  int o0,o1,o2,o3; \
  asm volatile( PRE_##d \
    XOP_##d("%[o0]","%[x0]") XOP_##d("%[o1]","%[x1]") \
    XOP_##d("%[o2]","%[x2]") XOP_##d("%[o3]","%[x3]") \
    WAIT_##d \
    "s_mov_b64 exec, %[m]\n\t" \
    "v_pk_min_f16 %[x0], %[x0], %[o0]\n\t" \
    "v_pk_min_f16 %[x1], %[x1], %[o1]\n\t" \
    "v_pk_min_f16 %[x2], %[x2], %[o2]\n\t" \
    "v_pk_min_f16 %[x3], %[x3], %[o3]\n\t" \
    "s_not_b64 exec, exec\n\t" \
    "v_pk_max_f16 %[x0], %[x0], %[o0]\n\t" \
    "v_pk_max_f16 %[x1], %[x1], %[o1]\n\t" \
    "v_pk_max_f16 %[x2], %[x2], %[o2]\n\t" \
    "v_pk_max_f16 %[x3], %[x3], %[o3]\n\t" \
    "s_mov_b64 exec, -1\n\t" \
    : [x0]"+v"(g0),[x1]"+v"(g1),[x2]"+v"(g2),[x3]"+v"(g3), \
      [o0]"=&v"(o0),[o1]"=&v"(o1),[o2]"=&v"(o2),[o3]"=&v"(o3) \
    : [m]"s"(M_)); }

__device__ __forceinline__ int pkmx(int a, int b) {
    int r; asm("v_pk_max_f16 %0, %1, %2" : "=v"(r) : "v"(a), "v"(b)); return r;
}
__device__ __forceinline__ int pkmn(int a, int b) {
    int r; asm("v_pk_min_f16 %0, %1, %2" : "=v"(r) : "v"(a), "v"(b)); return r;
}
// Register-level CE (d=16/32): compile-time direction -> pure rename.
#define RCE(A,B,FLIP) { int mn_ = pkmn(A,B), mx_ = pkmx(A,B); \
  if (FLIP) { A = mx_; B = mn_; } else { A = mn_; B = mx_; } }

// Applied only at writeout (monotonicity: top-k commutes with tanh).
__device__ __forceinline__ float fast_tanh(float s) {
    float e = __expf(2.0f * s);
    return fmaf(-2.0f, __builtin_amdgcn_rcpf(e + 1.0f), 1.0f);
}

__global__ __launch_bounds__(256, 8) void cnn_topk_kernel(
    const float* __restrict__ x,     // [B,1,H,W]
    const float* __restrict__ cw,    // [COUT,1,3,1]
    const float* __restrict__ cb,    // [COUT]
    float* __restrict__ out)         // [B,COUT,TOPK,W]
{
    __shared__ float xs[16 * CST];         // 13312 B, TRANSPOSED: [col][h+1]
    __shared__ int   obuf[TOPK_ * OST];    //  3400 B

    const int b   = blockIdx.x >> 1;
    const int wh  = blockIdx.x & 1;
    const int tid = threadIdx.x;
    const float* xb = x + (size_t)b * (H_ * W_) + wh * 16;

    // ---- stage 16 columns transposed -> xs[col][h+1], zero halos ----
    for (int i = tid; i < H_ * 4; i += 256) {       // coalesced float4 row reads
        int h = i >> 2, qg = (i & 3) * 4;
        float4 v = *reinterpret_cast<const float4*>(xb + h * W_ + qg);
        xs[(qg + 0) * CST + h + 1] = v.x;
        xs[(qg + 1) * CST + h + 1] = v.y;
        xs[(qg + 2) * CST + h + 1] = v.z;
        xs[(qg + 3) * CST + h + 1] = v.w;
    }
    if (tid < 16) {
        xs[tid * CST] = 0.0f;              // h = -1 halo
        xs[tid * CST + H_ + 1] = 0.0f;     // h = 200 halo
    }
    __syncthreads();

    const int wave = tid >> 6;
    const int lane = tid & 63;
    const int ln   = lane & 15;
    const int col  = wave * 4 + (lane >> 4);   // local column 0..15

    const int SENT = (int)0xFC00FC00;          // packed f16 -inf
    const bool tail_ok = (ln < 8);
    const int h3t = (192 + ln < H_) ? (192 + ln) : (H_ - 1);
    // taps for position h=CO+ln: idx CO+ln .. CO+ln+2 -> base + {CO, CO+1, CO+2}
    const float* xsf = &xs[col * CST + ln];    // immediate-offset reads -> ds_read2
    const float* xst = &xs[col * CST + h3t];   // tail base
    int* obase = &obuf[ln * OST + col];

#pragma unroll 1
    for (int cp = 0; cp < 8; ++cp) {
        const int coA = 2 * cp, coB = 2 * cp + 1;
        const float w0A = cw[coA * 3], w1A = cw[coA * 3 + 1], w2A = cw[coA * 3 + 2], bA = cb[coA];
        const float w0B = cw[coB * 3], w1B = cw[coB * 3 + 1], w2B = cw[coB * 3 + 2], bB = cb[coB];

        // conv only (tanh applied post-selection). h = CO + ln.
        int a0,a1,a2,a3,b0,b1,b2,b3,e0,e1,e2,e3,f0;
#define CONV1(VR, CO) { \
        float xm = xsf[(CO)], xc = xsf[(CO)+1], xp = xsf[(CO)+2]; \
        float sA = fmaf(w2A, xp, fmaf(w1A, xc, fmaf(w0A, xm, bA))); \
        float sB = fmaf(w2B, xp, fmaf(w1B, xc, fmaf(w0B, xm, bB))); \
        VR = __builtin_bit_cast(int, __builtin_amdgcn_cvt_pkrtz(sA, sB)); }
        CONV1(a0, 0)   CONV1(a1, 16)  CONV1(a2, 32)  CONV1(a3, 48)
        CONV1(b0, 64)  CONV1(b1, 80)  CONV1(b2, 96)  CONV1(b3, 112)
        CONV1(e0, 128) CONV1(e1, 144) CONV1(e2, 160) CONV1(e3, 176)
        { float xm = xst[0], xc = xst[1], xp = xst[2];
          float sA = fmaf(w2A, xp, fmaf(w1A, xc, fmaf(w0A, xm, bA)));
          float sB = fmaf(w2B, xp, fmaf(w1B, xc, fmaf(w0B, xm, bB)));
          int vt = __builtin_bit_cast(int, __builtin_amdgcn_cvt_pkrtz(sA, sB));
          f0 = tail_ok ? vt : SENT; }
#undef CONV1

        // ---- sort chunks 0..2 (asc,desc,asc), 64-sort each ----
        SRT_A(1, 2)                            // K=2
        SRT_A(2, 4) SRT_A(1, 4)                // K=4
        SRT_A(4, 8) SRT_A(2, 8) SRT_A(1, 8)    // K=8
        SRT_B(8) SRT_B(4) SRT_B(2) SRT_B(1)    // K=16
        RCE(a0,a1,0) RCE(a2,a3,1) RCE(b0,b1,1) RCE(b2,b3,0) RCE(e0,e1,0) RCE(e2,e3,1) // K=32 d16
        SRT_C(8) SRT_C(4) SRT_C(2) SRT_C(1)    // K=32
        RCE(a0,a2,0) RCE(a1,a3,0) RCE(b0,b2,1) RCE(b1,b3,1) RCE(e0,e2,0) RCE(e1,e3,0) // K=64 d32
        RCE(a0,a1,0) RCE(a2,a3,0) RCE(b0,b1,1) RCE(b2,b3,1) RCE(e0,e1,0) RCE(e2,e3,0) // K=64 d16
        SRT_A(8, 0) SRT_A(4, 0) SRT_A(2, 0) SRT_A(1, 0)   // K=64

        // ---- chunk3 sort-8 desc ----
        C3(1, 2) C3(2, 4) C3(1, 4) C3(4, 0) C3(2, 0) C3(1, 0)

        // ---- merges: top-64 of 256 ----
        int g0 = pkmx(a0, b0), g1 = pkmx(a1, b1), g2 = pkmx(a2, b2), g3 = pkmx(a3, b3);
        e0 = pkmx(e0, f0);                    // m2 = max(c2, c3); e1..e3 unchanged
        RCE(g0,g2,0) RCE(g1,g3,0) RCE(e0,e2,1) RCE(e1,e3,1)   // d32
        RCE(g0,g1,0) RCE(g2,g3,0) RCE(e0,e1,1) RCE(e2,e3,1)   // d16
        MRG8(8) MRG8(4) MRG8(2) MRG8(1)        // m1 asc, m2 desc
        g0 = pkmx(g0, e0); g1 = pkmx(g1, e1); g2 = pkmx(g2, e2); g3 = pkmx(g3, e3);
        RCE(g0,g2,1) RCE(g1,g3,1)              // d32 desc
        RCE(g0,g1,1) RCE(g2,g3,1)              // d16 desc
        FIN4(8) FIN4(4) FIN4(2) FIN4(1)        // sorted desc; rank = r*16+ln

        obase[0]            = g0;              // ranks  0..15
        obase[16 * OST]     = g1;              // ranks 16..31
        obase[32 * OST]     = g2;              // ranks 32..47
        if (ln < 2) obase[48 * OST] = g3;      // ranks 48,49
        __syncthreads();   // all 16 w of this cp in obuf

        // ---- coalesced write-out for this co-pair (800 entries) ----
#pragma unroll
        for (int j = 0; j < 4; ++j) {
            int idx = tid + j * 256;
            if (idx < 800) {
                int k = idx >> 4, w2 = idx & 15;
                HU u; u.i = obuf[k * OST + w2];
                size_t o0 = (((size_t)b * COUT_ + coA) * TOPK_ + k) * W_ + wh * 16 + w2;
                out[o0]                        = fast_tanh((float)u.h.x);
                out[o0 + (size_t)TOPK_ * W_]   = fast_tanh((float)u.h.y);
            }
        }
        __syncthreads();   // obuf free for next cp
    }
}

extern "C" void kernel_launch(void* const* d_in, const int* in_sizes, int n_in,
                              void* d_out, int out_size, void* d_ws, size_t ws_size,
                              hipStream_t stream) {
    const float* x  = (const float*)d_in[0];   // [1024,1,200,32]
    const float* cw = (const float*)d_in[1];   // [16,1,3,1]
    const float* cb = (const float*)d_in[2];   // [16]
    float* out = (float*)d_out;                // [1024,16,50,32]

    cnn_topk_kernel<<<dim3(B_ * 2), dim3(256), 0, stream>>>(x, cw, cb, out);
}